// Round 2
// baseline (342.905 us; speedup 1.0000x reference)
//
#include <hip/hip_runtime.h>

#define N_NODES 100000
#define N_EDGES 1600000
#define D 128
#define SUBW 64                       // dst-nodes per sub-bucket
#define NSUB 1563                     // ceil(N_NODES/SUBW)
#define CAP2 1408                     // per-sub capacity (mean 1024, sigma ~32 -> +12 sigma)
#define CHUNK2 2048                   // edges per binC block
#define BINC_BLOCKS ((N_EDGES + CHUNK2 - 1) / CHUNK2)   // 782
#define SUBSTRIDE 16                  // subcnt padded to one 64B line per sub (hot-line fix)

typedef __attribute__((ext_vector_type(8))) short short8;
typedef __attribute__((ext_vector_type(4))) float float4v;

__device__ inline unsigned short f2bf(float f) {
    unsigned u = __float_as_uint(f);
    unsigned r = (u + 0x7fffu + ((u >> 16) & 1u)) >> 16;   // RNE
    return (unsigned short)r;
}
__device__ inline float bflo(unsigned int p) { return __uint_as_float(p << 16); }
__device__ inline float bfhi(unsigned int p) { return __uint_as_float(p & 0xffff0000u); }

// dtype probe (bf16 flag=1 / fp32 flag=0) fused with b -> fp32 conversion
__global__ void probe_convert_kernel(const unsigned int* __restrict__ xw,
                                     const void* __restrict__ b,
                                     int* __restrict__ flag, float* __restrict__ bfv) {
    __shared__ int cnt;
    if (threadIdx.x == 0) cnt = 0;
    __syncthreads();
    unsigned low = xw[threadIdx.x] & 0xFFFFu;
    unsigned e = (low >> 7) & 0xFFu;
    atomicAdd(&cnt, (int)((e == 0u) || (e >= 107u && e <= 147u)));
    __syncthreads();
    int m = (cnt >= 192);
    if (threadIdx.x == 0) *flag = m;
    if (threadIdx.x < D)
        bfv[threadIdx.x] = m ? bflo(((const unsigned short*)b)[threadIdx.x])
                             : ((const float*)b)[threadIdx.x];
}

// Fine-bin edges by sub-bucket (sub = dst>>6) in ONE pass.
// Record = src(17b) | (dst&63)<<17 in 4 B. Per-BLOCK return-atomics only (R4/R6 lesson).
// INT LDS atomics only (R7 lesson).
// This round (serialized-shared-resource theory, after 4x-occupancy null result):
//  - deg[] global atomics DELETED (histogram folded into gemm from rec2)
//  - rec2 scatter uses NONTEMPORAL stores (no cross-XCD L2 line ownership ping-pong)
//  - subcnt padded to 1 cacheline/sub (per-line atomic serialization /16)
__global__ void binC_kernel(const int* __restrict__ src, const int* __restrict__ dst,
                            int* __restrict__ subcnt, unsigned* __restrict__ rec2) {
    __shared__ int lcnt[NSUB];
    __shared__ int lbase[NSUB];
    int tid = threadIdx.x;
    int e0 = blockIdx.x * CHUNK2;
    int e1 = e0 + CHUNK2 < N_EDGES ? e0 + CHUNK2 : N_EDGES;
    for (int s = tid; s < NSUB; s += 256) lcnt[s] = 0;
    __syncthreads();

    // pass 1: count per-sub. int4 loads: 4 edges in flight/thread.
    for (int i = e0 + tid * 4; i + 3 < e1; i += 1024) {
        int4 d4 = *(const int4*)&dst[i];
        atomicAdd(&lcnt[d4.x >> 6], 1);
        atomicAdd(&lcnt[d4.y >> 6], 1);
        atomicAdd(&lcnt[d4.z >> 6], 1);
        atomicAdd(&lcnt[d4.w >> 6], 1);
    }
    for (int i = e0 + (e1 - e0) / 4 * 4 + tid; i < e1; i += 256)
        atomicAdd(&lcnt[dst[i] >> 6], 1);
    __syncthreads();

    for (int s = tid; s < NSUB; s += 256) {
        int c = lcnt[s];
        lbase[s] = c ? atomicAdd(&subcnt[s * SUBSTRIDE], c) : 0;
        lcnt[s] = 0;
    }
    __syncthreads();

    // pass 2: place records with nontemporal stores.
    for (int i = e0 + tid * 4; i + 3 < e1; i += 1024) {
        int4 d4 = *(const int4*)&dst[i];
        int4 s4 = *(const int4*)&src[i];
        {
            int sub = d4.x >> 6;
            int pos = lbase[sub] + atomicAdd(&lcnt[sub], 1);
            if (pos < CAP2)
                __builtin_nontemporal_store((unsigned)s4.x | ((unsigned)(d4.x & 63) << 17),
                                            &rec2[(size_t)sub * CAP2 + pos]);
        }
        {
            int sub = d4.y >> 6;
            int pos = lbase[sub] + atomicAdd(&lcnt[sub], 1);
            if (pos < CAP2)
                __builtin_nontemporal_store((unsigned)s4.y | ((unsigned)(d4.y & 63) << 17),
                                            &rec2[(size_t)sub * CAP2 + pos]);
        }
        {
            int sub = d4.z >> 6;
            int pos = lbase[sub] + atomicAdd(&lcnt[sub], 1);
            if (pos < CAP2)
                __builtin_nontemporal_store((unsigned)s4.z | ((unsigned)(d4.z & 63) << 17),
                                            &rec2[(size_t)sub * CAP2 + pos]);
        }
        {
            int sub = d4.w >> 6;
            int pos = lbase[sub] + atomicAdd(&lcnt[sub], 1);
            if (pos < CAP2)
                __builtin_nontemporal_store((unsigned)s4.w | ((unsigned)(d4.w & 63) << 17),
                                            &rec2[(size_t)sub * CAP2 + pos]);
        }
    }
    for (int i = e0 + (e1 - e0) / 4 * 4 + tid; i < e1; i += 256) {
        int d = dst[i], s = src[i];
        int sub = d >> 6;
        int pos = lbase[sub] + atomicAdd(&lcnt[sub], 1);
        if (pos < CAP2)
            __builtin_nontemporal_store((unsigned)s | ((unsigned)(d & 63) << 17),
                                        &rec2[(size_t)sub * CAP2 + pos]);
    }
}

// h' = (x @ W) * rsqrt(deg+1) -> bf16 bits. MFMA 16x16x32 bf16, one wave per 16-row strip.
// Block bid covers rows [64*bid, 64*bid+64) == sub-bucket bid exactly, so the per-node
// degree is computed HERE as a 64-bin LDS histogram of rec2[bid] (replaces 1.6M global
// deg atomics in binC).
__global__ void gemm_kernel(const void* __restrict__ xv, const void* __restrict__ Wv,
                            const int* __restrict__ flag, const int* __restrict__ subcnt,
                            const unsigned* __restrict__ rec2,
                            unsigned short* __restrict__ h) {
    __shared__ unsigned short Wt[D * 136];  // W transposed [col][k], stride 136
    __shared__ int hist[SUBW];
    int tid = threadIdx.x;
    int bid = blockIdx.x;
    int m = *flag;
    if (tid < SUBW) hist[tid] = 0;
    for (int idx = tid; idx < D * D; idx += 256) {
        int k = idx >> 7, c = idx & 127;
        Wt[c * 136 + k] = m ? ((const unsigned short*)Wv)[idx]
                            : f2bf(((const float*)Wv)[idx]);
    }
    __syncthreads();

    int count = subcnt[bid * SUBSTRIDE]; if (count > CAP2) count = CAP2;
    const unsigned* rr = rec2 + (size_t)bid * CAP2;
    for (int i = tid; i < count; i += 256)
        atomicAdd(&hist[(rr[i] >> 17) & 63], 1);         // int LDS atomic: native
    __syncthreads();

    int wave = tid >> 6, lane = tid & 63;
    int row0 = (bid * 4 + wave) * 16;
    if (row0 >= N_NODES) return;
    int r = lane & 15, quad = lane >> 4;

    short8 a[4];  // a[t][j] = x[row0+r][t*32 + quad*8 + j]
    if (m) {
        const unsigned short* xr = (const unsigned short*)xv + (size_t)(row0 + r) * D + quad * 8;
        #pragma unroll
        for (int t = 0; t < 4; ++t) a[t] = *(const short8*)(xr + t * 32);
    } else {
        const float* xr = (const float*)xv + (size_t)(row0 + r) * D + quad * 8;
        #pragma unroll
        for (int t = 0; t < 4; ++t)
            for (int j = 0; j < 8; ++j) a[t][j] = (short)f2bf(xr[t * 32 + j]);
    }

    float sc[4];
    #pragma unroll
    for (int reg = 0; reg < 4; ++reg)
        sc[reg] = rsqrtf((float)(hist[wave * 16 + quad * 4 + reg] + 1));

    #pragma unroll
    for (int ct = 0; ct < 8; ++ct) {
        int col0 = ct * 16;
        float4v c = {0.f, 0.f, 0.f, 0.f};
        #pragma unroll
        for (int t = 0; t < 4; ++t) {
            short8 bfr = *(const short8*)&Wt[(col0 + r) * 136 + t * 32 + quad * 8];
            c = __builtin_amdgcn_mfma_f32_16x16x32_bf16(a[t], bfr, c, 0, 0, 0);
        }
        #pragma unroll
        for (int reg = 0; reg < 4; ++reg) {
            int orow = row0 + quad * 4 + reg;  // C/D: col=lane&15, row=quad*4+reg
            h[(size_t)orow * D + col0 + r] = f2bf(c[reg] * sc[reg]);
        }
    }
}

// One block per sub-bucket: LDS counting-sort of records by local node, then the
// R6-measured register-accumulate gather (quarter-wave uint4, 4 edges in flight),
// butterfly combine, fused self+rsqrt+bias+relu epilogue. NO fp32 LDS atomics.
__global__ void __launch_bounds__(256) agg3_kernel(
        const unsigned* __restrict__ rec2, const int* __restrict__ subcnt,
        const float* __restrict__ bfv, const int* __restrict__ flag,
        const unsigned short* __restrict__ h, void* __restrict__ out) {
    __shared__ unsigned srt[CAP2];     // sorted src indices (5.6 KB)
    __shared__ int hist[SUBW];
    __shared__ int ofs[SUBW];
    __shared__ int place[SUBW];
    __shared__ float lbias[D];

    int sub = blockIdx.x, tid = threadIdx.x;
    int n0 = sub * SUBW;
    if (tid < SUBW) hist[tid] = 0;
    if (tid < D) lbias[tid] = bfv[tid];
    __syncthreads();

    int count = subcnt[sub * SUBSTRIDE]; if (count > CAP2) count = CAP2;
    const unsigned* r = rec2 + (size_t)sub * CAP2;

    for (int i = tid; i < count; i += 256)
        atomicAdd(&hist[(r[i] >> 17) & 63], 1);          // int LDS atomic: native
    __syncthreads();
    if (tid == 0) {
        int s = 0;
        for (int k = 0; k < SUBW; ++k) { ofs[k] = s; place[k] = s; s += hist[k]; }
    }
    __syncthreads();
    for (int i = tid; i < count; i += 256) {
        unsigned w = r[i];
        int p = atomicAdd(&place[(w >> 17) & 63], 1);
        srt[p] = w & 0x1FFFFu;
    }
    __syncthreads();

    const uint4* h4 = (const uint4*)h;                   // h row = 16 uint4
    int wave = tid >> 6, lane = tid & 63;
    int q = lane >> 4, c16 = lane & 15;
    int m = *flag;

    for (int t = 0; t < 16; ++t) {
        int nl = wave * 16 + t;
        int n = n0 + nl;
        if (n >= N_NODES) break;
        int o = ofs[nl], cnt = hist[nl];
        int e_end = o + cnt;

        float acc[8] = {0.f, 0.f, 0.f, 0.f, 0.f, 0.f, 0.f, 0.f};
        for (int j = o + q; j < e_end; j += 4) {
            unsigned s = srt[j];                         // same-addr LDS read: broadcast
            uint4 p = h4[(size_t)s * 16 + c16];
            acc[0] += bflo(p.x); acc[1] += bfhi(p.x);
            acc[2] += bflo(p.y); acc[3] += bfhi(p.y);
            acc[4] += bflo(p.z); acc[5] += bfhi(p.z);
            acc[6] += bflo(p.w); acc[7] += bfhi(p.w);
        }
        #pragma unroll
        for (int i = 0; i < 8; ++i) {
            acc[i] += __shfl_xor(acc[i], 16);
            acc[i] += __shfl_xor(acc[i], 32);
        }

        if (q == 0) {
            uint4 sp = h4[(size_t)n * 16 + c16];         // self term (dis[src] folded in h')
            float dn = rsqrtf((float)(cnt + 1));
            float v[8];
            v[0] = fmaxf(dn * (acc[0] + bflo(sp.x)) + lbias[c16 * 8 + 0], 0.f);
            v[1] = fmaxf(dn * (acc[1] + bfhi(sp.x)) + lbias[c16 * 8 + 1], 0.f);
            v[2] = fmaxf(dn * (acc[2] + bflo(sp.y)) + lbias[c16 * 8 + 2], 0.f);
            v[3] = fmaxf(dn * (acc[3] + bfhi(sp.y)) + lbias[c16 * 8 + 3], 0.f);
            v[4] = fmaxf(dn * (acc[4] + bflo(sp.z)) + lbias[c16 * 8 + 4], 0.f);
            v[5] = fmaxf(dn * (acc[5] + bfhi(sp.z)) + lbias[c16 * 8 + 5], 0.f);
            v[6] = fmaxf(dn * (acc[6] + bflo(sp.w)) + lbias[c16 * 8 + 6], 0.f);
            v[7] = fmaxf(dn * (acc[7] + bfhi(sp.w)) + lbias[c16 * 8 + 7], 0.f);
            if (m) {
                uint4 pk;
                pk.x = ((unsigned)f2bf(v[1]) << 16) | f2bf(v[0]);
                pk.y = ((unsigned)f2bf(v[3]) << 16) | f2bf(v[2]);
                pk.z = ((unsigned)f2bf(v[5]) << 16) | f2bf(v[4]);
                pk.w = ((unsigned)f2bf(v[7]) << 16) | f2bf(v[6]);
                ((uint4*)out)[(size_t)n * 16 + c16] = pk;
            } else {
                float4 f0 = make_float4(v[0], v[1], v[2], v[3]);
                float4 f1 = make_float4(v[4], v[5], v[6], v[7]);
                float4* of = (float4*)((float*)out + (size_t)n * D + c16 * 8);
                of[0] = f0; of[1] = f1;
            }
        }
    }
}

extern "C" void kernel_launch(void* const* d_in, const int* in_sizes, int n_in,
                              void* d_out, int out_size, void* d_ws, size_t ws_size,
                              hipStream_t stream) {
    const void* x = nullptr; const int* ei = nullptr;
    const void* W = nullptr; const void* b = nullptr;
    for (int i = 0; i < n_in; ++i) {
        if      (in_sizes[i] == N_NODES * D) x  = d_in[i];
        else if (in_sizes[i] == 2 * N_EDGES) ei = (const int*)d_in[i];
        else if (in_sizes[i] == D * D)       W  = d_in[i];
        else if (in_sizes[i] == D)           b  = d_in[i];
    }
    if (!x || !ei || !W || !b) {
        x = d_in[0]; ei = (const int*)d_in[1]; W = d_in[2]; b = d_in[3];
    }
    const int* src = ei;            // edge_index[0]
    const int* dst = ei + N_EDGES;  // edge_index[1]

    // ws: flag(16B) | subcnt NSUB*16 (line-padded) | bfv 128 f32 | rec2 NSUB*CAP2 u32 | h N*D bf16
    char* ws = (char*)d_ws;
    int*      flag   = (int*)ws;
    int*      subcnt = (int*)(ws + 16);
    float*    bfv    = (float*)(subcnt + NSUB * SUBSTRIDE);
    unsigned* rec2   = (unsigned*)(bfv + D);
    unsigned short* h = (unsigned short*)(rec2 + (size_t)NSUB * CAP2);

    hipMemsetAsync(subcnt, 0, sizeof(int) * NSUB * SUBSTRIDE, stream);

    probe_convert_kernel<<<1, 256, 0, stream>>>((const unsigned int*)x, b, flag, bfv);

    binC_kernel<<<BINC_BLOCKS, 256, 0, stream>>>(src, dst, subcnt, rec2);

    gemm_kernel<<<NSUB, 256, 0, stream>>>(x, W, flag, subcnt, rec2, h);

    agg3_kernel<<<NSUB, 256, 0, stream>>>(rec2, subcnt, bfv, flag, h, d_out);
}

// Round 4
// 279.267 us; speedup vs baseline: 1.2279x; 1.2279x over previous
//
#include <hip/hip_runtime.h>

#define N_NODES 100000
#define N_EDGES 1600000
#define D 128
#define SUBW 64                       // dst-nodes per agg sub-bucket
#define NSUB 1563                     // ceil(N_NODES/SUBW)
#define CAP2 1408                     // per-sub matched capacity (mean 1024, +12 sigma)
#define NC 98                         // coarse buckets of 1024 nodes (dst>>10)
#define CAPC 20480                    // per-bucket cap: 16327 mean + 2932 mean pad + 7.8 sigma (R3 bug: was 18432 -> ~830 slots/bucket dropped)
#define CHUNK3 4096                   // edges per binD block
#define BIND_BLOCKS ((N_EDGES + CHUNK3 - 1) / CHUNK3)   // 391
#define STAGE_MAX (CHUNK3 + NC * 16)  // 5664 staging slots (counts padded to 16)
#define CCSTRIDE 16                   // ccnt padded to one 64B line per bucket

typedef __attribute__((ext_vector_type(8))) short short8;
typedef __attribute__((ext_vector_type(4))) float float4v;

__device__ inline unsigned short f2bf(float f) {
    unsigned u = __float_as_uint(f);
    unsigned r = (u + 0x7fffu + ((u >> 16) & 1u)) >> 16;   // RNE
    return (unsigned short)r;
}
__device__ inline float bflo(unsigned int p) { return __uint_as_float(p << 16); }
__device__ inline float bfhi(unsigned int p) { return __uint_as_float(p & 0xffff0000u); }

// dtype probe (bf16 flag=1 / fp32 flag=0) fused with b -> fp32 conversion
__global__ void probe_convert_kernel(const unsigned int* __restrict__ xw,
                                     const void* __restrict__ b,
                                     int* __restrict__ flag, float* __restrict__ bfv) {
    __shared__ int cnt;
    if (threadIdx.x == 0) cnt = 0;
    __syncthreads();
    unsigned low = xw[threadIdx.x] & 0xFFFFu;
    unsigned e = (low >> 7) & 0xFFu;
    atomicAdd(&cnt, (int)((e == 0u) || (e >= 107u && e <= 147u)));
    __syncthreads();
    int m = (cnt >= 192);
    if (threadIdx.x == 0) *flag = m;
    if (threadIdx.x < D)
        bfv[threadIdx.x] = m ? bflo(((const unsigned short*)b)[threadIdx.x])
                             : ((const float*)b)[threadIdx.x];
}

// Coarse radix partition: edges -> 98 buckets of 1024 dst-nodes.
// Record = src(17b) | (dst&1023)<<17. Sentinel 0xFFFFFFFF pads claims to 16 records
// so every block's global run is 64B-aligned -> FULL-LINE writes only, one owner per
// line. (R2 lesson: the old per-sub 4B scatter wrote 97MB of random 64B granules at
// the ~1 TB/s random-write wall; payload is 6.4MB.)
__global__ void __launch_bounds__(256) binD_kernel(
        const int* __restrict__ src, const int* __restrict__ dst,
        int* __restrict__ ccnt, unsigned* __restrict__ recg) {
    __shared__ __align__(16) unsigned stg[STAGE_MAX];   // 22.6 KB
    __shared__ int cnt[NC], cpad[NC], ofs[NC], base[NC], place[NC];
    __shared__ int tot;

    int tid = threadIdx.x;
    int e0 = blockIdx.x * CHUNK3;
    int e1 = e0 + CHUNK3 < N_EDGES ? e0 + CHUNK3 : N_EDGES;
    if (tid < NC) cnt[tid] = 0;
    __syncthreads();

    // pass A: count per coarse bucket (int4: 4 edges in flight)
    for (int i = e0 + tid * 4; i + 3 < e1; i += 1024) {
        int4 d4 = *(const int4*)&dst[i];
        atomicAdd(&cnt[d4.x >> 10], 1);
        atomicAdd(&cnt[d4.y >> 10], 1);
        atomicAdd(&cnt[d4.z >> 10], 1);
        atomicAdd(&cnt[d4.w >> 10], 1);
    }
    for (int i = e0 + (e1 - e0) / 4 * 4 + tid; i < e1; i += 256)
        atomicAdd(&cnt[dst[i] >> 10], 1);
    __syncthreads();

    // claim 16-aligned global ranges per bucket
    if (tid < NC) {
        int c = cnt[tid];
        int p = (c + 15) & ~15;
        cpad[tid] = p;
        base[tid] = p ? atomicAdd(&ccnt[tid * CCSTRIDE], p) : 0;
    }
    __syncthreads();
    if (tid == 0) {
        int s = 0;
        for (int k = 0; k < NC; ++k) { ofs[k] = s; place[k] = s; s += cpad[k]; }
        tot = s;
    }
    __syncthreads();
    // sentinel-fill the pad slots
    if (tid < NC) {
        int e = ofs[tid] + cpad[tid];
        for (int j = ofs[tid] + cnt[tid]; j < e; ++j) stg[j] = 0xFFFFFFFFu;
    }
    __syncthreads();

    // pass C: place records into LDS staging, bucket-sorted
    for (int i = e0 + tid * 4; i + 3 < e1; i += 1024) {
        int4 d4 = *(const int4*)&dst[i];
        int4 s4 = *(const int4*)&src[i];
        { int b = d4.x >> 10; int p = atomicAdd(&place[b], 1);
          stg[p] = (unsigned)s4.x | ((unsigned)(d4.x & 1023) << 17); }
        { int b = d4.y >> 10; int p = atomicAdd(&place[b], 1);
          stg[p] = (unsigned)s4.y | ((unsigned)(d4.y & 1023) << 17); }
        { int b = d4.z >> 10; int p = atomicAdd(&place[b], 1);
          stg[p] = (unsigned)s4.z | ((unsigned)(d4.z & 1023) << 17); }
        { int b = d4.w >> 10; int p = atomicAdd(&place[b], 1);
          stg[p] = (unsigned)s4.w | ((unsigned)(d4.w & 1023) << 17); }
    }
    for (int i = e0 + (e1 - e0) / 4 * 4 + tid; i < e1; i += 256) {
        int d = dst[i], s = src[i];
        int b = d >> 10; int p = atomicAdd(&place[b], 1);
        stg[p] = (unsigned)s | ((unsigned)(d & 1023) << 17);
    }
    __syncthreads();

    // flush: uint4 per thread; 16-aligned runs => a 4-slot group never straddles buckets
    int tot_ = tot;
    for (int j = tid * 4; j < tot_; j += 1024) {
        int lo = 0, hi = NC - 1;
        while (lo < hi) { int mid = (lo + hi + 1) >> 1; if (ofs[mid] <= j) lo = mid; else hi = mid - 1; }
        int gi = base[lo] + (j - ofs[lo]);
        if (gi < CAPC)
            *(uint4*)&recg[(size_t)lo * CAPC + gi] = *(const uint4*)&stg[j];
    }
}

// Per-node in-degree: one block per coarse bucket, private 1024-bin LDS histogram.
__global__ void __launch_bounds__(256) deg_kernel(
        const unsigned* __restrict__ recg, const int* __restrict__ ccnt,
        int* __restrict__ deg) {
    __shared__ int hist[1024];
    int b = blockIdx.x, tid = threadIdx.x;
    for (int t = tid; t < 1024; t += 256) hist[t] = 0;
    __syncthreads();
    int count = ccnt[b * CCSTRIDE]; if (count > CAPC) count = CAPC;
    const unsigned* r = recg + (size_t)b * CAPC;
    for (int i = tid * 4; i + 3 < count; i += 1024) {   // count % 16 == 0
        uint4 w4 = *(const uint4*)&r[i];
        if (w4.x != 0xFFFFFFFFu) atomicAdd(&hist[w4.x >> 17], 1);
        if (w4.y != 0xFFFFFFFFu) atomicAdd(&hist[w4.y >> 17], 1);
        if (w4.z != 0xFFFFFFFFu) atomicAdd(&hist[w4.z >> 17], 1);
        if (w4.w != 0xFFFFFFFFu) atomicAdd(&hist[w4.w >> 17], 1);
    }
    __syncthreads();
    for (int t = tid; t < 1024; t += 256) {
        int n = b * 1024 + t;
        if (n < N_NODES) deg[n] = hist[t];
    }
}

// h' = (x @ W) * rsqrt(deg+1) -> bf16 bits. MFMA 16x16x32 bf16, one wave per 16-row strip.
__global__ void gemm_kernel(const void* __restrict__ xv, const void* __restrict__ Wv,
                            const int* __restrict__ flag, const int* __restrict__ deg,
                            unsigned short* __restrict__ h) {
    __shared__ unsigned short Wt[D * 136];  // W transposed [col][k], stride 136
    int tid = threadIdx.x;
    int m = *flag;
    for (int idx = tid; idx < D * D; idx += 256) {
        int k = idx >> 7, c = idx & 127;
        Wt[c * 136 + k] = m ? ((const unsigned short*)Wv)[idx]
                            : f2bf(((const float*)Wv)[idx]);
    }
    __syncthreads();

    int wave = tid >> 6, lane = tid & 63;
    int row0 = (blockIdx.x * 4 + wave) * 16;
    if (row0 >= N_NODES) return;
    int r = lane & 15, quad = lane >> 4;

    short8 a[4];  // a[t][j] = x[row0+r][t*32 + quad*8 + j]
    if (m) {
        const unsigned short* xr = (const unsigned short*)xv + (size_t)(row0 + r) * D + quad * 8;
        #pragma unroll
        for (int t = 0; t < 4; ++t) a[t] = *(const short8*)(xr + t * 32);
    } else {
        const float* xr = (const float*)xv + (size_t)(row0 + r) * D + quad * 8;
        #pragma unroll
        for (int t = 0; t < 4; ++t)
            for (int j = 0; j < 8; ++j) a[t][j] = (short)f2bf(xr[t * 32 + j]);
    }

    float sc[4];
    #pragma unroll
    for (int reg = 0; reg < 4; ++reg)
        sc[reg] = rsqrtf((float)(deg[row0 + quad * 4 + reg] + 1));

    #pragma unroll
    for (int ct = 0; ct < 8; ++ct) {
        int col0 = ct * 16;
        float4v c = {0.f, 0.f, 0.f, 0.f};
        #pragma unroll
        for (int t = 0; t < 4; ++t) {
            short8 bfr = *(const short8*)&Wt[(col0 + r) * 136 + t * 32 + quad * 8];
            c = __builtin_amdgcn_mfma_f32_16x16x32_bf16(a[t], bfr, c, 0, 0, 0);
        }
        #pragma unroll
        for (int reg = 0; reg < 4; ++reg) {
            int orow = row0 + quad * 4 + reg;  // C/D: col=lane&15, row=quad*4+reg
            h[(size_t)orow * D + col0 + r] = f2bf(c[reg] * sc[reg]);
        }
    }
}

// One block per sub-bucket (64 nodes): filter-scan the parent coarse bucket
// ((rec>>23)==sub&15; sentinels auto-fail), LDS counting-sort matches by local node,
// then the proven register-accumulate gather + butterfly + fused epilogue.
__global__ void __launch_bounds__(256) agg3_kernel(
        const unsigned* __restrict__ recg, const int* __restrict__ ccnt,
        const float* __restrict__ bfv, const int* __restrict__ flag,
        const unsigned short* __restrict__ h, void* __restrict__ out) {
    __shared__ unsigned srtA[CAP2];    // matched records (unsorted)
    __shared__ unsigned srt[CAP2];     // sorted src indices
    __shared__ int hist[SUBW];
    __shared__ int ofs[SUBW];
    __shared__ int place[SUBW];
    __shared__ float lbias[D];
    __shared__ int nmatch;

    int sub = blockIdx.x, tid = threadIdx.x;
    int n0 = sub * SUBW;
    int B = sub >> 4;
    unsigned subLocal = (unsigned)(sub & 15);
    if (tid < SUBW) hist[tid] = 0;
    if (tid < D) lbias[tid] = bfv[tid];
    if (tid == 0) nmatch = 0;
    __syncthreads();

    int count = ccnt[B * CCSTRIDE]; if (count > CAPC) count = CAPC;
    const unsigned* r = recg + (size_t)B * CAPC;
    for (int i = tid * 4; i + 3 < count; i += 1024) {   // count % 16 == 0
        uint4 w4 = *(const uint4*)&r[i];
        if ((w4.x >> 23) == subLocal) { int p = atomicAdd(&nmatch, 1); if (p < CAP2) srtA[p] = w4.x; }
        if ((w4.y >> 23) == subLocal) { int p = atomicAdd(&nmatch, 1); if (p < CAP2) srtA[p] = w4.y; }
        if ((w4.z >> 23) == subLocal) { int p = atomicAdd(&nmatch, 1); if (p < CAP2) srtA[p] = w4.z; }
        if ((w4.w >> 23) == subLocal) { int p = atomicAdd(&nmatch, 1); if (p < CAP2) srtA[p] = w4.w; }
    }
    __syncthreads();
    int cnt_m = nmatch; if (cnt_m > CAP2) cnt_m = CAP2;

    for (int i = tid; i < cnt_m; i += 256)
        atomicAdd(&hist[(srtA[i] >> 17) & 63], 1);       // int LDS atomic: native
    __syncthreads();
    if (tid == 0) {
        int s = 0;
        for (int k = 0; k < SUBW; ++k) { ofs[k] = s; place[k] = s; s += hist[k]; }
    }
    __syncthreads();
    for (int i = tid; i < cnt_m; i += 256) {
        unsigned w = srtA[i];
        int p = atomicAdd(&place[(w >> 17) & 63], 1);
        srt[p] = w & 0x1FFFFu;
    }
    __syncthreads();

    const uint4* h4 = (const uint4*)h;                   // h row = 16 uint4
    int wave = tid >> 6, lane = tid & 63;
    int q = lane >> 4, c16 = lane & 15;
    int m = *flag;

    for (int t = 0; t < 16; ++t) {
        int nl = wave * 16 + t;
        int n = n0 + nl;
        if (n >= N_NODES) break;
        int o = ofs[nl], cnt = hist[nl];
        int e_end = o + cnt;

        float acc[8] = {0.f, 0.f, 0.f, 0.f, 0.f, 0.f, 0.f, 0.f};
        for (int j = o + q; j < e_end; j += 4) {
            unsigned s = srt[j];                         // same-addr LDS read: broadcast
            uint4 p = h4[(size_t)s * 16 + c16];
            acc[0] += bflo(p.x); acc[1] += bfhi(p.x);
            acc[2] += bflo(p.y); acc[3] += bfhi(p.y);
            acc[4] += bflo(p.z); acc[5] += bfhi(p.z);
            acc[6] += bflo(p.w); acc[7] += bfhi(p.w);
        }
        #pragma unroll
        for (int i = 0; i < 8; ++i) {
            acc[i] += __shfl_xor(acc[i], 16);
            acc[i] += __shfl_xor(acc[i], 32);
        }

        if (q == 0) {
            uint4 sp = h4[(size_t)n * 16 + c16];         // self term (dis[src] folded in h')
            float dn = rsqrtf((float)(cnt + 1));
            float v[8];
            v[0] = fmaxf(dn * (acc[0] + bflo(sp.x)) + lbias[c16 * 8 + 0], 0.f);
            v[1] = fmaxf(dn * (acc[1] + bfhi(sp.x)) + lbias[c16 * 8 + 1], 0.f);
            v[2] = fmaxf(dn * (acc[2] + bflo(sp.y)) + lbias[c16 * 8 + 2], 0.f);
            v[3] = fmaxf(dn * (acc[3] + bfhi(sp.y)) + lbias[c16 * 8 + 3], 0.f);
            v[4] = fmaxf(dn * (acc[4] + bflo(sp.z)) + lbias[c16 * 8 + 4], 0.f);
            v[5] = fmaxf(dn * (acc[5] + bfhi(sp.z)) + lbias[c16 * 8 + 5], 0.f);
            v[6] = fmaxf(dn * (acc[6] + bflo(sp.w)) + lbias[c16 * 8 + 6], 0.f);
            v[7] = fmaxf(dn * (acc[7] + bfhi(sp.w)) + lbias[c16 * 8 + 7], 0.f);
            if (m) {
                uint4 pk;
                pk.x = ((unsigned)f2bf(v[1]) << 16) | f2bf(v[0]);
                pk.y = ((unsigned)f2bf(v[3]) << 16) | f2bf(v[2]);
                pk.z = ((unsigned)f2bf(v[5]) << 16) | f2bf(v[4]);
                pk.w = ((unsigned)f2bf(v[7]) << 16) | f2bf(v[6]);
                ((uint4*)out)[(size_t)n * 16 + c16] = pk;
            } else {
                float4 f0 = make_float4(v[0], v[1], v[2], v[3]);
                float4 f1 = make_float4(v[4], v[5], v[6], v[7]);
                float4* of = (float4*)((float*)out + (size_t)n * D + c16 * 8);
                of[0] = f0; of[1] = f1;
            }
        }
    }
}

extern "C" void kernel_launch(void* const* d_in, const int* in_sizes, int n_in,
                              void* d_out, int out_size, void* d_ws, size_t ws_size,
                              hipStream_t stream) {
    const void* x = nullptr; const int* ei = nullptr;
    const void* W = nullptr; const void* b = nullptr;
    for (int i = 0; i < n_in; ++i) {
        if      (in_sizes[i] == N_NODES * D) x  = d_in[i];
        else if (in_sizes[i] == 2 * N_EDGES) ei = (const int*)d_in[i];
        else if (in_sizes[i] == D * D)       W  = d_in[i];
        else if (in_sizes[i] == D)           b  = d_in[i];
    }
    if (!x || !ei || !W || !b) {
        x = d_in[0]; ei = (const int*)d_in[1]; W = d_in[2]; b = d_in[3];
    }
    const int* src = ei;            // edge_index[0]
    const int* dst = ei + N_EDGES;  // edge_index[1]

    // ws: flag 16B | ccnt NC*16 ints | bfv 128 f32 | deg 100352 ints |
    //     recg NC*CAPC u32 (8.0MB) | h N*D bf16 (25.6MB)
    char* ws = (char*)d_ws;
    int*      flag = (int*)ws;
    int*      ccnt = (int*)(ws + 16);
    float*    bfv  = (float*)(ccnt + NC * CCSTRIDE);
    int*      deg  = (int*)(bfv + D);
    unsigned* recg = (unsigned*)(deg + 100352);
    unsigned short* h = (unsigned short*)(recg + (size_t)NC * CAPC);

    hipMemsetAsync(ccnt, 0, sizeof(int) * NC * CCSTRIDE, stream);

    probe_convert_kernel<<<1, 256, 0, stream>>>((const unsigned int*)x, b, flag, bfv);

    binD_kernel<<<BIND_BLOCKS, 256, 0, stream>>>(src, dst, ccnt, recg);

    deg_kernel<<<NC, 256, 0, stream>>>(recg, ccnt, deg);

    gemm_kernel<<<NSUB, 256, 0, stream>>>(x, W, flag, deg, h);

    agg3_kernel<<<NSUB, 256, 0, stream>>>(recg, ccnt, bfv, flag, h, d_out);
}

// Round 5
// 276.052 us; speedup vs baseline: 1.2422x; 1.0116x over previous
//
#include <hip/hip_runtime.h>

#define N_NODES 100000
#define N_EDGES 1600000
#define D 128
#define SUBW 64                       // dst-nodes per agg sub-bucket
#define NSUB 1563                     // ceil(N_NODES/SUBW)
#define NC 98                         // coarse buckets of 1024 nodes (dst>>10)
#define CAPC 20480                    // per-bucket raw cap (16327 mean + 2932 mean pad + 7.8 sigma)
#define CAP3 18432                    // per-bucket sorted cap (16327 mean + 16 sigma), %16==0
#define CAPS 2048                     // per-sub staged slice cap (mean 1024, +32 sigma)
#define CHUNK3 4096                   // edges per binD block
#define BIND_BLOCKS ((N_EDGES + CHUNK3 - 1) / CHUNK3)   // 391
#define STAGE_MAX (CHUNK3 + NC * 16)  // 5664 staging slots (counts padded to 16)
#define CCSTRIDE 16                   // ccnt padded to one 64B line per bucket

typedef __attribute__((ext_vector_type(8))) short short8;
typedef __attribute__((ext_vector_type(4))) float float4v;

__device__ inline unsigned short f2bf(float f) {
    unsigned u = __float_as_uint(f);
    unsigned r = (u + 0x7fffu + ((u >> 16) & 1u)) >> 16;   // RNE
    return (unsigned short)r;
}
__device__ inline float bflo(unsigned int p) { return __uint_as_float(p << 16); }
__device__ inline float bfhi(unsigned int p) { return __uint_as_float(p & 0xffff0000u); }

// dtype probe (bf16 flag=1 / fp32 flag=0) fused with b -> fp32 conversion
__global__ void probe_convert_kernel(const unsigned int* __restrict__ xw,
                                     const void* __restrict__ b,
                                     int* __restrict__ flag, float* __restrict__ bfv) {
    __shared__ int cnt;
    if (threadIdx.x == 0) cnt = 0;
    __syncthreads();
    unsigned low = xw[threadIdx.x] & 0xFFFFu;
    unsigned e = (low >> 7) & 0xFFu;
    atomicAdd(&cnt, (int)((e == 0u) || (e >= 107u && e <= 147u)));
    __syncthreads();
    int m = (cnt >= 192);
    if (threadIdx.x == 0) *flag = m;
    if (threadIdx.x < D)
        bfv[threadIdx.x] = m ? bflo(((const unsigned short*)b)[threadIdx.x])
                             : ((const float*)b)[threadIdx.x];
}

// Coarse radix partition: edges -> 98 buckets of 1024 dst-nodes.
// Record = src(17b) | (dst&1023)<<17. Sentinel 0xFFFFFFFF pads claims to 16 records
// -> FULL-LINE writes only (R2 lesson: 4B scatter = 97MB random-granule wall).
__global__ void __launch_bounds__(256) binD_kernel(
        const int* __restrict__ src, const int* __restrict__ dst,
        int* __restrict__ ccnt, unsigned* __restrict__ recg) {
    __shared__ __align__(16) unsigned stg[STAGE_MAX];   // 22.6 KB
    __shared__ int cnt[NC], cpad[NC], ofs[NC], base[NC], place[NC];
    __shared__ int tot;

    int tid = threadIdx.x;
    int e0 = blockIdx.x * CHUNK3;
    int e1 = e0 + CHUNK3 < N_EDGES ? e0 + CHUNK3 : N_EDGES;
    if (tid < NC) cnt[tid] = 0;
    __syncthreads();

    for (int i = e0 + tid * 4; i + 3 < e1; i += 1024) {
        int4 d4 = *(const int4*)&dst[i];
        atomicAdd(&cnt[d4.x >> 10], 1);
        atomicAdd(&cnt[d4.y >> 10], 1);
        atomicAdd(&cnt[d4.z >> 10], 1);
        atomicAdd(&cnt[d4.w >> 10], 1);
    }
    for (int i = e0 + (e1 - e0) / 4 * 4 + tid; i < e1; i += 256)
        atomicAdd(&cnt[dst[i] >> 10], 1);
    __syncthreads();

    if (tid < NC) {
        int c = cnt[tid];
        int p = (c + 15) & ~15;
        cpad[tid] = p;
        base[tid] = p ? atomicAdd(&ccnt[tid * CCSTRIDE], p) : 0;
    }
    __syncthreads();
    if (tid == 0) {
        int s = 0;
        for (int k = 0; k < NC; ++k) { ofs[k] = s; place[k] = s; s += cpad[k]; }
        tot = s;
    }
    __syncthreads();
    if (tid < NC) {
        int e = ofs[tid] + cpad[tid];
        for (int j = ofs[tid] + cnt[tid]; j < e; ++j) stg[j] = 0xFFFFFFFFu;
    }
    __syncthreads();

    for (int i = e0 + tid * 4; i + 3 < e1; i += 1024) {
        int4 d4 = *(const int4*)&dst[i];
        int4 s4 = *(const int4*)&src[i];
        { int b = d4.x >> 10; int p = atomicAdd(&place[b], 1);
          stg[p] = (unsigned)s4.x | ((unsigned)(d4.x & 1023) << 17); }
        { int b = d4.y >> 10; int p = atomicAdd(&place[b], 1);
          stg[p] = (unsigned)s4.y | ((unsigned)(d4.y & 1023) << 17); }
        { int b = d4.z >> 10; int p = atomicAdd(&place[b], 1);
          stg[p] = (unsigned)s4.z | ((unsigned)(d4.z & 1023) << 17); }
        { int b = d4.w >> 10; int p = atomicAdd(&place[b], 1);
          stg[p] = (unsigned)s4.w | ((unsigned)(d4.w & 1023) << 17); }
    }
    for (int i = e0 + (e1 - e0) / 4 * 4 + tid; i < e1; i += 256) {
        int d = dst[i], s = src[i];
        int b = d >> 10; int p = atomicAdd(&place[b], 1);
        stg[p] = (unsigned)s | ((unsigned)(d & 1023) << 17);
    }
    __syncthreads();

    int tot_ = tot;
    for (int j = tid * 4; j < tot_; j += 1024) {
        int lo = 0, hi = NC - 1;
        while (lo < hi) { int mid = (lo + hi + 1) >> 1; if (ofs[mid] <= j) lo = mid; else hi = mid - 1; }
        int gi = base[lo] + (j - ofs[lo]);
        if (gi < CAPC)
            *(uint4*)&recg[(size_t)lo * CAPC + gi] = *(const uint4*)&stg[j];
    }
}

// One block per coarse bucket: 1024-bin histogram -> deg[] + nodeofs[] (prefix),
// then counting-sort the bucket's records by local node (LDS scatter, full-line
// flush IN PLACE over the bucket's own recg region). Kills agg3's 16x filter
// re-scan (128 MB of the 295 MB FETCH) and its per-block sort phases.
__global__ void __launch_bounds__(256) sortdeg_kernel(
        unsigned* __restrict__ recg, const int* __restrict__ ccnt,
        int* __restrict__ deg, int* __restrict__ nodeofs) {
    __shared__ int hist[1024];
    __shared__ int ofs[1024];
    __shared__ int place[1024];
    __shared__ int wsum[4];
    __shared__ __align__(16) unsigned s_srt[CAP3];   // 72 KB

    int b = blockIdx.x, tid = threadIdx.x;
    for (int t = tid; t < 1024; t += 256) hist[t] = 0;
    __syncthreads();
    int count = ccnt[b * CCSTRIDE]; if (count > CAPC) count = CAPC;
    const unsigned* r = recg + (size_t)b * CAPC;
    for (int i = tid * 4; i + 3 < count; i += 1024) {   // count % 16 == 0
        uint4 w4 = *(const uint4*)&r[i];
        if (w4.x != 0xFFFFFFFFu) atomicAdd(&hist[w4.x >> 17], 1);
        if (w4.y != 0xFFFFFFFFu) atomicAdd(&hist[w4.y >> 17], 1);
        if (w4.z != 0xFFFFFFFFu) atomicAdd(&hist[w4.z >> 17], 1);
        if (w4.w != 0xFFFFFFFFu) atomicAdd(&hist[w4.w >> 17], 1);
    }
    __syncthreads();

    // exclusive prefix over 1024 bins: thread owns bins [4t,4t+4); shfl scan across waves
    int h0 = hist[tid * 4], h1 = hist[tid * 4 + 1];
    int h2 = hist[tid * 4 + 2], h3 = hist[tid * 4 + 3];
    int tot_t = h0 + h1 + h2 + h3;
    int lane = tid & 63, wave = tid >> 6;
    int v = tot_t;
    #pragma unroll
    for (int dsh = 1; dsh < 64; dsh <<= 1) {
        int u = __shfl_up(v, dsh);
        if (lane >= dsh) v += u;
    }
    if (lane == 63) wsum[wave] = v;
    __syncthreads();
    int wbase = 0;
    #pragma unroll
    for (int k = 0; k < 4; ++k) if (k < wave) wbase += wsum[k];
    int e0v = wbase + v - tot_t;
    ofs[tid * 4]     = e0v;           place[tid * 4]     = e0v;
    ofs[tid * 4 + 1] = e0v + h0;      place[tid * 4 + 1] = e0v + h0;
    ofs[tid * 4 + 2] = e0v + h0 + h1; place[tid * 4 + 2] = e0v + h0 + h1;
    ofs[tid * 4 + 3] = e0v + h0 + h1 + h2;
    place[tid * 4 + 3] = e0v + h0 + h1 + h2;
    // deg + nodeofs (unconditional: arrays sized NC*1024; rows >= N_NODES never read)
    int n4 = b * 1024 + tid * 4;
    *(int4*)&deg[n4]     = make_int4(h0, h1, h2, h3);
    *(int4*)&nodeofs[n4] = make_int4(e0v, e0v + h0, e0v + h0 + h1, e0v + h0 + h1 + h2);
    __syncthreads();

    // scatter pass: records -> node-sorted LDS (src index only; position encodes node)
    for (int i = tid * 4; i + 3 < count; i += 1024) {
        uint4 w4 = *(const uint4*)&r[i];
        if (w4.x != 0xFFFFFFFFu) { int p = atomicAdd(&place[w4.x >> 17], 1); if (p < CAP3) s_srt[p] = w4.x & 0x1FFFFu; }
        if (w4.y != 0xFFFFFFFFu) { int p = atomicAdd(&place[w4.y >> 17], 1); if (p < CAP3) s_srt[p] = w4.y & 0x1FFFFu; }
        if (w4.z != 0xFFFFFFFFu) { int p = atomicAdd(&place[w4.z >> 17], 1); if (p < CAP3) s_srt[p] = w4.z & 0x1FFFFu; }
        if (w4.w != 0xFFFFFFFFu) { int p = atomicAdd(&place[w4.w >> 17], 1); if (p < CAP3) s_srt[p] = w4.w & 0x1FFFFu; }
    }
    __syncthreads();

    // flush in place (this block owns recg[b] exclusively; full-line uint4 writes)
    int total = ofs[1023] + hist[1023];
    int totR = (total + 15) & ~15; if (totR > CAP3) totR = CAP3;
    unsigned* w = recg + (size_t)b * CAPC;
    for (int j = tid * 4; j < totR; j += 1024)
        *(uint4*)&w[j] = *(const uint4*)&s_srt[j];
}

// h' = (x @ W) * rsqrt(deg+1) -> bf16 bits. MFMA 16x16x32 bf16, one wave per 16-row strip.
__global__ void gemm_kernel(const void* __restrict__ xv, const void* __restrict__ Wv,
                            const int* __restrict__ flag, const int* __restrict__ deg,
                            unsigned short* __restrict__ h) {
    __shared__ unsigned short Wt[D * 136];  // W transposed [col][k], stride 136
    int tid = threadIdx.x;
    int m = *flag;
    for (int idx = tid; idx < D * D; idx += 256) {
        int k = idx >> 7, c = idx & 127;
        Wt[c * 136 + k] = m ? ((const unsigned short*)Wv)[idx]
                            : f2bf(((const float*)Wv)[idx]);
    }
    __syncthreads();

    int wave = tid >> 6, lane = tid & 63;
    int row0 = (blockIdx.x * 4 + wave) * 16;
    if (row0 >= N_NODES) return;
    int r = lane & 15, quad = lane >> 4;

    short8 a[4];  // a[t][j] = x[row0+r][t*32 + quad*8 + j]
    if (m) {
        const unsigned short* xr = (const unsigned short*)xv + (size_t)(row0 + r) * D + quad * 8;
        #pragma unroll
        for (int t = 0; t < 4; ++t) a[t] = *(const short8*)(xr + t * 32);
    } else {
        const float* xr = (const float*)xv + (size_t)(row0 + r) * D + quad * 8;
        #pragma unroll
        for (int t = 0; t < 4; ++t)
            for (int j = 0; j < 8; ++j) a[t][j] = (short)f2bf(xr[t * 32 + j]);
    }

    float sc[4];
    #pragma unroll
    for (int reg = 0; reg < 4; ++reg)
        sc[reg] = rsqrtf((float)(deg[row0 + quad * 4 + reg] + 1));

    #pragma unroll
    for (int ct = 0; ct < 8; ++ct) {
        int col0 = ct * 16;
        float4v c = {0.f, 0.f, 0.f, 0.f};
        #pragma unroll
        for (int t = 0; t < 4; ++t) {
            short8 bfr = *(const short8*)&Wt[(col0 + r) * 136 + t * 32 + quad * 8];
            c = __builtin_amdgcn_mfma_f32_16x16x32_bf16(a[t], bfr, c, 0, 0, 0);
        }
        #pragma unroll
        for (int reg = 0; reg < 4; ++reg) {
            int orow = row0 + quad * 4 + reg;  // C/D: col=lane&15, row=quad*4+reg
            h[(size_t)orow * D + col0 + r] = f2bf(c[reg] * sc[reg]);
        }
    }
}

// One block per 64-node sub: load 64 offsets + the contiguous node-sorted src slice
// (mean 4KB), then the proven quarter-wave gather + butterfly + fused epilogue.
// No scan, no sort, no LDS atomics (all moved to sortdeg once per bucket).
__global__ void __launch_bounds__(256) agg4_kernel(
        const unsigned* __restrict__ srt2, const int* __restrict__ nodeofs,
        const int* __restrict__ deg,
        const float* __restrict__ bfv, const int* __restrict__ flag,
        const unsigned short* __restrict__ h, void* __restrict__ out) {
    __shared__ unsigned srt[CAPS];     // 8 KB
    __shared__ int l_ofs[SUBW];
    __shared__ int l_deg[SUBW];
    __shared__ float lbias[D];

    int sub = blockIdx.x, tid = threadIdx.x;
    int n0 = sub * SUBW;
    int B = sub >> 4, loc0 = (sub & 15) * SUBW;
    if (tid < SUBW) {
        l_ofs[tid] = nodeofs[B * 1024 + loc0 + tid];
        int n = n0 + tid;
        l_deg[tid] = (n < N_NODES) ? deg[n] : 0;
    }
    if (tid < D) lbias[tid] = bfv[tid];
    __syncthreads();

    int base0 = l_ofs[0];
    int span = (l_ofs[SUBW - 1] + l_deg[SUBW - 1]) - base0;
    if (span > CAPS) span = CAPS;
    if (span > CAP3 - base0) span = CAP3 - base0;
    const unsigned* sb = srt2 + (size_t)B * CAPC + base0;
    for (int i = tid; i < span; i += 256) srt[i] = sb[i];
    __syncthreads();

    const uint4* h4 = (const uint4*)h;                   // h row = 16 uint4
    int wave = tid >> 6, lane = tid & 63;
    int q = lane >> 4, c16 = lane & 15;
    int m = *flag;

    for (int t = 0; t < 16; ++t) {
        int nl = wave * 16 + t;
        int n = n0 + nl;
        if (n >= N_NODES) break;
        int o = l_ofs[nl] - base0;
        int cnt = l_deg[nl];
        int e_end = o + cnt; if (e_end > span) e_end = span;

        float acc[8] = {0.f, 0.f, 0.f, 0.f, 0.f, 0.f, 0.f, 0.f};
        for (int j = o + q; j < e_end; j += 4) {
            unsigned s = srt[j];                         // same-addr LDS read: broadcast
            uint4 p = h4[(size_t)s * 16 + c16];
            acc[0] += bflo(p.x); acc[1] += bfhi(p.x);
            acc[2] += bflo(p.y); acc[3] += bfhi(p.y);
            acc[4] += bflo(p.z); acc[5] += bfhi(p.z);
            acc[6] += bflo(p.w); acc[7] += bfhi(p.w);
        }
        #pragma unroll
        for (int i = 0; i < 8; ++i) {
            acc[i] += __shfl_xor(acc[i], 16);
            acc[i] += __shfl_xor(acc[i], 32);
        }

        if (q == 0) {
            uint4 sp = h4[(size_t)n * 16 + c16];         // self term (dis[src] folded in h')
            float dn = rsqrtf((float)(cnt + 1));
            float v[8];
            v[0] = fmaxf(dn * (acc[0] + bflo(sp.x)) + lbias[c16 * 8 + 0], 0.f);
            v[1] = fmaxf(dn * (acc[1] + bfhi(sp.x)) + lbias[c16 * 8 + 1], 0.f);
            v[2] = fmaxf(dn * (acc[2] + bflo(sp.y)) + lbias[c16 * 8 + 2], 0.f);
            v[3] = fmaxf(dn * (acc[3] + bfhi(sp.y)) + lbias[c16 * 8 + 3], 0.f);
            v[4] = fmaxf(dn * (acc[4] + bflo(sp.z)) + lbias[c16 * 8 + 4], 0.f);
            v[5] = fmaxf(dn * (acc[5] + bfhi(sp.z)) + lbias[c16 * 8 + 5], 0.f);
            v[6] = fmaxf(dn * (acc[6] + bflo(sp.w)) + lbias[c16 * 8 + 6], 0.f);
            v[7] = fmaxf(dn * (acc[7] + bfhi(sp.w)) + lbias[c16 * 8 + 7], 0.f);
            if (m) {
                uint4 pk;
                pk.x = ((unsigned)f2bf(v[1]) << 16) | f2bf(v[0]);
                pk.y = ((unsigned)f2bf(v[3]) << 16) | f2bf(v[2]);
                pk.z = ((unsigned)f2bf(v[5]) << 16) | f2bf(v[4]);
                pk.w = ((unsigned)f2bf(v[7]) << 16) | f2bf(v[6]);
                ((uint4*)out)[(size_t)n * 16 + c16] = pk;
            } else {
                float4 f0 = make_float4(v[0], v[1], v[2], v[3]);
                float4 f1 = make_float4(v[4], v[5], v[6], v[7]);
                float4* of = (float4*)((float*)out + (size_t)n * D + c16 * 8);
                of[0] = f0; of[1] = f1;
            }
        }
    }
}

extern "C" void kernel_launch(void* const* d_in, const int* in_sizes, int n_in,
                              void* d_out, int out_size, void* d_ws, size_t ws_size,
                              hipStream_t stream) {
    const void* x = nullptr; const int* ei = nullptr;
    const void* W = nullptr; const void* b = nullptr;
    for (int i = 0; i < n_in; ++i) {
        if      (in_sizes[i] == N_NODES * D) x  = d_in[i];
        else if (in_sizes[i] == 2 * N_EDGES) ei = (const int*)d_in[i];
        else if (in_sizes[i] == D * D)       W  = d_in[i];
        else if (in_sizes[i] == D)           b  = d_in[i];
    }
    if (!x || !ei || !W || !b) {
        x = d_in[0]; ei = (const int*)d_in[1]; W = d_in[2]; b = d_in[3];
    }
    const int* src = ei;            // edge_index[0]
    const int* dst = ei + N_EDGES;  // edge_index[1]

    // ws: flag 16B | ccnt NC*16 ints | bfv 128 f32 | deg NC*1024 ints |
    //     nodeofs NC*1024 ints | recg NC*CAPC u32 (8.0MB, re-sorted in place) |
    //     h N*D bf16 (25.6MB)
    char* ws = (char*)d_ws;
    int*      flag    = (int*)ws;
    int*      ccnt    = (int*)(ws + 16);
    float*    bfv     = (float*)(ccnt + NC * CCSTRIDE);
    int*      deg     = (int*)(bfv + D);
    int*      nodeofs = deg + NC * 1024;
    unsigned* recg    = (unsigned*)(nodeofs + NC * 1024);
    unsigned short* h = (unsigned short*)(recg + (size_t)NC * CAPC);

    hipMemsetAsync(ccnt, 0, sizeof(int) * NC * CCSTRIDE, stream);

    probe_convert_kernel<<<1, 256, 0, stream>>>((const unsigned int*)x, b, flag, bfv);

    binD_kernel<<<BIND_BLOCKS, 256, 0, stream>>>(src, dst, ccnt, recg);

    sortdeg_kernel<<<NC, 256, 0, stream>>>(recg, ccnt, deg, nodeofs);

    gemm_kernel<<<NSUB, 256, 0, stream>>>(x, W, flag, deg, h);

    agg4_kernel<<<NSUB, 256, 0, stream>>>(recg, nodeofs, deg, bfv, flag, h, d_out);
}